// Round 10
// baseline (230.868 us; speedup 1.0000x reference)
//
#include <hip/hip_runtime.h>
#include <math.h>

// Conv-KNRM on MI355X. B=128, QLEN=30, DLEN=256, EMB=300 (pad 320), C=128.
//
// 2 dispatches:
//   prep      : wt2 bf16 frag-order [plane(6)][cb(8)][ec(10)][lane(64)][8];
//               zero cnt[128].
//   conv_pool : 640 blocks x 512 thr. Blocks 0..511 = doc 64-row tiles
//               (b=bi>>2, l0=(bi&3)*64); 512..639 = query 32-row tiles.
//               Stage x fp32->bf16 to LDS; wave = one cb (16ch x 3 grams);
//               A=w frags from global (L2); no K-loop barriers;
//               bias+relu+L2norm -> bf16 [g][b][l][c].
//               Then fence + atomicAdd(cnt[b]); the 5th finisher for b runs
//               pool+final for b (3 tg x MFMA cos x RBF x11 -> pf -> log/dot
//               -> out[b]). Device-scope fences, no co-residency assumption.
//
// ws (shorts): wt2@0 (245760) | qn@245760 (1474560) | dn@1720320 (12582912)
//              | cnt (int[128]) @ short-offset 14303232

typedef __bf16 bf16x8 __attribute__((ext_vector_type(8)));
typedef float f32x4 __attribute__((ext_vector_type(4)));

#if __has_builtin(__builtin_amdgcn_exp2f)
#define EXP2F(x) __builtin_amdgcn_exp2f(x)
#else
#define EXP2F(x) exp2f(x)
#endif

#define AS_STRIDE 344  // shorts; 688 B row: 2-way b128 (free), 16B-aligned

static __device__ __forceinline__ unsigned short f2bf(float f) {
  union { float f; unsigned int u; } v; v.f = f;
  unsigned int r = v.u + 0x7FFFu + ((v.u >> 16) & 1u);  // RNE
  return (unsigned short)(r >> 16);
}

// blocks [0,960): weights -> frag order; block 960: zero cnt
__global__ __launch_bounds__(256) void prep(
    const float* __restrict__ w1, const float* __restrict__ w2,
    const float* __restrict__ w3,
    unsigned short* __restrict__ wt2, int* __restrict__ cnt) {
  const int bid = blockIdx.x;
  const int t = threadIdx.x;
  if (bid < 960) {
    int idx = bid * 256 + t;
    if (idx >= 245760) return;
    int jj   = idx & 7;
    int lane = (idx >> 3) & 63;
    int ec   = (idx >> 9) % 10;
    int cb   = (idx / 5120) & 7;
    int p    = idx / 40960;
    const float* w; int k, jt;
    if (p == 0)      { w = w1; k = 1; jt = 0; }
    else if (p <= 2) { w = w2; k = 2; jt = p - 1; }
    else             { w = w3; k = 3; jt = p - 3; }
    int c = cb * 16 + (lane & 15);
    int e = ec * 32 + (lane >> 4) * 8 + jj;
    float v = (e < 300) ? w[(c * 300 + e) * k + jt] : 0.0f;
    wt2[idx] = f2bf(v);
  } else {
    if (t < 128) cnt[t] = 0;
  }
}

// Wave tile: NI*16 l-rows x 48 ch (cb=w: 16 ch in each of 3 grams).
// A-operand = weights (frag-order global), B = x rows (LDS).
// D: ch = cb*16 + quad*4 + r, l = ni*16 + lrow.
template<int NI>
__device__ __forceinline__ void conv_body(
    unsigned short* As, float* psq,  // psq[8][3][NI*16]
    const float* __restrict__ xb, int L, int l0, int b,
    const unsigned short* __restrict__ wt2,
    const float* __restrict__ b1, const float* __restrict__ b2,
    const float* __restrict__ b3,
    unsigned short* __restrict__ out) {
  constexpr int ROWS = NI * 16 + 2;
  constexpr int NR = NI * 16;
  const int t = threadIdx.x;
  const int w = __builtin_amdgcn_readfirstlane(t >> 6);  // cb 0..7
  const int lane = t & 63;
  const int quad = lane >> 4, lrow = lane & 15;

  // stage A: fp32 -> bf16, rows l0..l0+ROWS-1, e 0..319 (zero pad)
  for (int idx = t; idx < ROWS * 80; idx += 512) {
    int r = idx / 80, e4 = idx % 80;
    int e = e4 * 4;
    int l = l0 + r;
    float4 v = make_float4(0.f, 0.f, 0.f, 0.f);
    if (l < L && e < 300) v = *reinterpret_cast<const float4*>(xb + (size_t)l * 300 + e);
    unsigned int lo = (unsigned int)f2bf(v.x) | ((unsigned int)f2bf(v.y) << 16);
    unsigned int hi = (unsigned int)f2bf(v.z) | ((unsigned int)f2bf(v.w) << 16);
    *reinterpret_cast<uint2*>(&As[r * AS_STRIDE + e]) = make_uint2(lo, hi);
  }
  __syncthreads();

  f32x4 acc[NI][3];
  #pragma unroll
  for (int ni = 0; ni < NI; ++ni)
    #pragma unroll
    for (int g = 0; g < 3; ++g) acc[ni][g] = (f32x4){0.f, 0.f, 0.f, 0.f};

  const unsigned short* wl = wt2 + (size_t)lane * 8;

  #pragma unroll 2
  for (int ec = 0; ec < 10; ++ec) {
    #pragma unroll
    for (int j = 0; j < 3; ++j) {
      bf16x8 xf[NI];
      #pragma unroll
      for (int ni = 0; ni < NI; ++ni)
        xf[ni] = *reinterpret_cast<const bf16x8*>(
            &As[(ni * 16 + lrow + j) * AS_STRIDE + ec * 32 + quad * 8]);
      #pragma unroll
      for (int g = j; g < 3; ++g) {
        const int pst = (g * (g + 1)) >> 1;
        bf16x8 wf = *reinterpret_cast<const bf16x8*>(
            wl + ((((pst + j) * 8 + w) * 10 + ec) << 9));
        #pragma unroll
        for (int ni = 0; ni < NI; ++ni)
          acc[ni][g] = __builtin_amdgcn_mfma_f32_16x16x32_bf16(
              wf, xf[ni], acc[ni][g], 0, 0, 0);
      }
    }
  }

  const float* biases[3] = {b1, b2, b3};
  float4 bv[3];
  #pragma unroll
  for (int g = 0; g < 3; ++g)
    bv[g] = *reinterpret_cast<const float4*>(biases[g] + w * 16 + quad * 4);

  // per-wave ssq: register sums -> 2 shfls -> per-wave LDS slot
  #pragma unroll
  for (int ni = 0; ni < NI; ++ni) {
    #pragma unroll
    for (int g = 0; g < 3; ++g) {
      float p = 0.f;
      #pragma unroll
      for (int r = 0; r < 4; ++r) {
        float y = fmaxf(acc[ni][g][r] + bv[g][r], 0.f);
        p += y * y;
      }
      p += __shfl_xor(p, 16);
      p += __shfl_xor(p, 32);
      if (lane < 16) psq[(w * 3 + g) * NR + ni * 16 + lrow] = p;
    }
  }
  __syncthreads();

  #pragma unroll
  for (int ni = 0; ni < NI; ++ni) {
    int row = ni * 16 + lrow;
    int l = l0 + row;
    if (l < L) {
      #pragma unroll
      for (int g = 0; g < 3; ++g) {
        float ssq = 0.f;
        #pragma unroll
        for (int wv = 0; wv < 8; ++wv) ssq += psq[(wv * 3 + g) * NR + row];
        float inv = 1.0f / (sqrtf(ssq) + 1e-13f);
        unsigned int pk[2];
        #pragma unroll
        for (int h = 0; h < 2; ++h) {
          float y0 = fmaxf(acc[ni][g][2 * h + 0] + bv[g][2 * h + 0], 0.f) * inv;
          float y1 = fmaxf(acc[ni][g][2 * h + 1] + bv[g][2 * h + 1], 0.f) * inv;
          pk[h] = (unsigned int)f2bf(y0) | ((unsigned int)f2bf(y1) << 16);
        }
        unsigned short* op = out + ((size_t)(g * 128 + b) * L + l) * 128 +
                             w * 16 + quad * 4;
        *reinterpret_cast<uint2*>(op) = make_uint2(pk[0], pk[1]);
      }
    }
  }
}

__global__ __launch_bounds__(512, 4) void conv_pool(
    const float* __restrict__ qemb, const float* __restrict__ demb,
    const float* __restrict__ qmask, const float* __restrict__ dmask,
    const float* __restrict__ b1, const float* __restrict__ b2,
    const float* __restrict__ b3, const float* __restrict__ dw,
    const unsigned short* __restrict__ wt2,
    unsigned short* __restrict__ qn, unsigned short* __restrict__ dn,
    int* __restrict__ cnt, float* __restrict__ out) {
  __shared__ unsigned short As[66 * AS_STRIDE];  // 45408 B
  __shared__ float psq[8 * 3 * 64];              // 6144 B (reused as pf/part)
  __shared__ int lastFlag;

  const int bi = blockIdx.x;
  const int t = threadIdx.x;
  int b;
  if (bi < 512) {
    b = bi >> 2;
    conv_body<4>(As, psq, demb + (size_t)b * 256 * 300, 256,
                 (bi & 3) * 64, b, wt2, b1, b2, b3, dn);
  } else {
    b = bi - 512;
    conv_body<2>(As, psq, qemb + (size_t)b * 30 * 300, 30,
                 0, b, wt2, b1, b2, b3, qn);
  }

  // release this block's stores device-wide, then count in
  __syncthreads();  // all stores issued & drained (barrier implies vmcnt(0))
  if (t == 0) {
    __threadfence();  // L2 writeback to coherence point
    lastFlag = (atomicAdd(&cnt[b], 1) == 4);
  }
  __syncthreads();
  if (!lastFlag) return;

  // ---- pool + final for batch b (5th finisher only) ----
  __threadfence();  // acquire: invalidate stale copies

  const float MU[11] = {1.0f, 0.9f, 0.7f, 0.5f, 0.3f, 0.1f,
                        -0.1f, -0.3f, -0.5f, -0.7f, -0.9f};
  const float NEGC[11] = {-721347.52f, -72.134752f, -72.134752f, -72.134752f,
                          -72.134752f, -72.134752f, -72.134752f, -72.134752f,
                          -72.134752f, -72.134752f, -72.134752f};
  float* pf = psq;           // 990 floats
  float* part = psq + 1024;  // 8 floats

  const int wv = t >> 6, lane = t & 63;
  const int quad = lane >> 4, l15 = lane & 15;
  const int d0 = wv * 32;

  float dmv[2][4];
  #pragma unroll
  for (int mi = 0; mi < 2; ++mi)
    #pragma unroll
    for (int r = 0; r < 4; ++r)
      dmv[mi][r] = dmask[b * 256 + d0 + mi * 16 + quad * 4 + r];

  float qmv[2];
  qmv[0] = qmask[b * 30 + l15];
  qmv[1] = (16 + l15 < 30) ? qmask[b * 30 + 16 + l15] : 0.0f;

  float s = 0.f;

  #pragma unroll 1
  for (int tg = 0; tg < 3; ++tg) {
    __syncthreads();  // pf free (prev iter readers done)
    for (int idx = t; idx < 990; idx += 512) pf[idx] = 0.f;

    const unsigned short* dslab = dn + (size_t)(tg * 128 + b) * 256 * 128;
    bf16x8 aD[2][4];
    #pragma unroll
    for (int mi = 0; mi < 2; ++mi)
      #pragma unroll
      for (int kt = 0; kt < 4; ++kt)
        aD[mi][kt] = *reinterpret_cast<const bf16x8*>(
            dslab + (size_t)(d0 + mi * 16 + l15) * 128 + kt * 32 + quad * 8);

    __syncthreads();  // pf zero visible

    #pragma unroll 1
    for (int ig = 0; ig < 3; ++ig) {
      const unsigned short* qslab = qn + (size_t)(ig * 128 + b) * 30 * 128;

      bf16x8 bQ[2][4];
      #pragma unroll
      for (int ni = 0; ni < 2; ++ni)
        #pragma unroll
        for (int kt = 0; kt < 4; ++kt)
          bQ[ni][kt] = *reinterpret_cast<const bf16x8*>(
              qslab + (size_t)(ni * 16 + l15) * 128 + kt * 32 + quad * 8);

      f32x4 acc[2][2];
      #pragma unroll
      for (int mi = 0; mi < 2; ++mi)
        #pragma unroll
        for (int ni = 0; ni < 2; ++ni) acc[mi][ni] = (f32x4){0.f, 0.f, 0.f, 0.f};

      #pragma unroll
      for (int kt = 0; kt < 4; ++kt)
        #pragma unroll
        for (int mi = 0; mi < 2; ++mi)
          #pragma unroll
          for (int ni = 0; ni < 2; ++ni)
            acc[mi][ni] = __builtin_amdgcn_mfma_f32_16x16x32_bf16(
                aD[mi][kt], bQ[ni][kt], acc[mi][ni], 0, 0, 0);

      float feat[2][11];
      #pragma unroll
      for (int ni = 0; ni < 2; ++ni)
        #pragma unroll
        for (int kk = 0; kk < 11; ++kk) feat[ni][kk] = 0.0f;

      #pragma unroll
      for (int mi = 0; mi < 2; ++mi) {
        #pragma unroll
        for (int r = 0; r < 4; ++r) {
          #pragma unroll
          for (int ni = 0; ni < 2; ++ni) {
            float m  = qmv[ni] * dmv[mi][r];
            float cm = acc[mi][ni][r] * m;
            #pragma unroll
            for (int kk = 0; kk < 11; ++kk) {
              float d2 = cm - MU[kk];
              feat[ni][kk] += EXP2F(d2 * d2 * NEGC[kk]) * m;
            }
          }
        }
      }

      #pragma unroll
      for (int ni = 0; ni < 2; ++ni)
        #pragma unroll
        for (int kk = 0; kk < 11; ++kk) {
          float v = feat[ni][kk];
          v += __shfl_xor(v, 16);
          v += __shfl_xor(v, 32);
          feat[ni][kk] = v;
        }

      if (quad == 0) {
        #pragma unroll
        for (int ni = 0; ni < 2; ++ni) {
          int q = ni * 16 + l15;
          if (q < 30) {
            #pragma unroll
            for (int kk = 0; kk < 11; ++kk)
              atomicAdd(&pf[(ig * 30 + q) * 11 + kk], feat[ni][kk]);
          }
        }
      }
    }
    __syncthreads();

    for (int idx = t; idx < 990; idx += 512) {
      int ig = idx / 330;
      int rem = idx % 330;
      int q  = rem / 11;
      int kk = rem % 11;
      s += __logf(fmaxf(pf[idx], 1e-10f)) * 0.01f * qmask[b * 30 + q] *
           dw[(ig * 3 + tg) * 11 + kk];
    }
  }

  s += __shfl_xor(s, 1);  s += __shfl_xor(s, 2);  s += __shfl_xor(s, 4);
  s += __shfl_xor(s, 8);  s += __shfl_xor(s, 16); s += __shfl_xor(s, 32);
  __syncthreads();
  if (lane == 0) part[wv] = s;
  __syncthreads();
  if (t == 0) {
    float tot = 0.f;
    #pragma unroll
    for (int i = 0; i < 8; ++i) tot += part[i];
    out[b] = tot;  // sole writer for this b
  }
}

extern "C" void kernel_launch(void* const* d_in, const int* in_sizes, int n_in,
                              void* d_out, int out_size, void* d_ws, size_t ws_size,
                              hipStream_t stream) {
  const float* qemb  = (const float*)d_in[0];
  const float* demb  = (const float*)d_in[1];
  const float* qmask = (const float*)d_in[2];
  const float* dmask = (const float*)d_in[3];
  const float* w1 = (const float*)d_in[4];
  const float* b1 = (const float*)d_in[5];
  const float* w2 = (const float*)d_in[6];
  const float* b2 = (const float*)d_in[7];
  const float* w3 = (const float*)d_in[8];
  const float* b3 = (const float*)d_in[9];
  const float* dw = (const float*)d_in[10];

  unsigned short* ws  = (unsigned short*)d_ws;
  unsigned short* wt2 = ws;                    // 245760
  unsigned short* qn  = ws + 245760;           // 1474560
  unsigned short* dn  = ws + 1720320;          // 12582912
  int*            cnt = (int*)(ws + 14303232); // 128 ints
  float* out = (float*)d_out;

  prep<<<961, 256, 0, stream>>>(w1, w2, w3, wt2, cnt);
  conv_pool<<<640, 512, 0, stream>>>(qemb, demb, qmask, dmask,
                                     b1, b2, b3, dw, wt2, qn, dn, cnt, out);
}

// Round 11
// 179.325 us; speedup vs baseline: 1.2874x; 1.2874x over previous
//
#include <hip/hip_runtime.h>
#include <math.h>

// Conv-KNRM on MI355X. B=128, QLEN=30, DLEN=256, EMB=300 (pad 320), C=128.
//
// 4 dispatches (best-known split, R7≈181us, bodies re-tuned):
//   prep      : wt2 bf16 frag-order [plane(6)][cb(8)][ec(10)][lane(64)][8];
//               qemb/demb fp32 -> bf16 rows [*][320].
//   conv_all  : 640 blocks x 512 thr (8 waves; wave = one cb: 16ch x 3 grams).
//               Doc 64-row tiles / query 32-row. A=w frags global (L2),
//               B=x rows LDS. psq aliased over As (LDS 45.4KB -> 3 blk/CU).
//               bias+relu+L2norm, packed uint2 -> bf16 [g][b][l][c].
//   pool_mfma : 3072 single-wave blocks (tg,b,dchunk32). MFMA cos, fma-form
//               RBF x11, quad shfl d-sum -> pkq8 partials.
//   final     : sum 8 chunks, log/clip/qmask/sum_q dot dense_w -> out[128].
//
// ws (shorts): wt2@0 (245760) | qx@245760 (1310720) | dx@1556480 (10485760)
//              | qn@12042240 (1474560) | dn@13516800 (12582912)
// pkq8 (f32 12.2MB) aliased over qx/dx (dead after conv_all).

typedef __bf16 bf16x8 __attribute__((ext_vector_type(8)));
typedef float f32x4 __attribute__((ext_vector_type(4)));

#if __has_builtin(__builtin_amdgcn_exp2f)
#define EXP2F(x) __builtin_amdgcn_exp2f(x)
#else
#define EXP2F(x) exp2f(x)
#endif

#define AS_STRIDE 344  // shorts; 688 B row: 2-way b128 (free), 16B-aligned

static __device__ __forceinline__ unsigned short f2bf(float f) {
  union { float f; unsigned int u; } v; v.f = f;
  unsigned int r = v.u + 0x7FFFu + ((v.u >> 16) & 1u);  // RNE
  return (unsigned short)(r >> 16);
}

// blocks [0,960): weights -> frag order; [960,6720): x -> bf16
__global__ __launch_bounds__(256) void prep(
    const float* __restrict__ w1, const float* __restrict__ w2,
    const float* __restrict__ w3,
    const float* __restrict__ qemb, const float* __restrict__ demb,
    unsigned short* __restrict__ wt2,
    unsigned short* __restrict__ qx, unsigned short* __restrict__ dx) {
  const int bid = blockIdx.x;
  const int t = threadIdx.x;
  if (bid < 960) {
    int idx = bid * 256 + t;
    if (idx >= 245760) return;
    int jj   = idx & 7;
    int lane = (idx >> 3) & 63;
    int ec   = (idx >> 9) % 10;
    int cb   = (idx / 5120) & 7;
    int p    = idx / 40960;
    const float* w; int k, jt;
    if (p == 0)      { w = w1; k = 1; jt = 0; }
    else if (p <= 2) { w = w2; k = 2; jt = p - 1; }
    else             { w = w3; k = 3; jt = p - 3; }
    int c = cb * 16 + (lane & 15);
    int e = ec * 32 + (lane >> 4) * 8 + jj;
    float v = (e < 300) ? w[(c * 300 + e) * k + jt] : 0.0f;
    wt2[idx] = f2bf(v);
  } else {
    int idx = (bid - 960) * 256 + t;
    if (idx >= 1474560) return;
    int c8   = idx % 40;
    int ridx = idx / 40;
    const float* src; unsigned short* dst; int valid;
    if (ridx < 4096) {
      int b = ridx >> 5, r = ridx & 31;
      valid = (r < 30);
      src = qemb + ((size_t)b * 30 + r) * 300;
      dst = qx + (size_t)ridx * 320;
    } else {
      int rd = ridx - 4096;
      valid = 1;
      src = demb + (size_t)rd * 300;
      dst = dx + (size_t)rd * 320;
    }
    int e = c8 * 8;
    float4 a = make_float4(0.f, 0.f, 0.f, 0.f);
    float4 c = make_float4(0.f, 0.f, 0.f, 0.f);
    if (valid && e < 300)     a = *reinterpret_cast<const float4*>(src + e);
    if (valid && e + 4 < 300) c = *reinterpret_cast<const float4*>(src + e + 4);
    uint4 o;
    o.x = (unsigned int)f2bf(a.x) | ((unsigned int)f2bf(a.y) << 16);
    o.y = (unsigned int)f2bf(a.z) | ((unsigned int)f2bf(a.w) << 16);
    o.z = (unsigned int)f2bf(c.x) | ((unsigned int)f2bf(c.y) << 16);
    o.w = (unsigned int)f2bf(c.z) | ((unsigned int)f2bf(c.w) << 16);
    *reinterpret_cast<uint4*>(dst + e) = o;
  }
}

// Wave tile: NI*16 l-rows x 48 ch (cb=w: 16 ch in each of 3 grams).
// A-operand = weights (frag-order global), B = x rows (LDS).
// D: ch = cb*16 + quad*4 + r, l = ni*16 + lrow.
template<int NI>
__device__ __forceinline__ void conv_body(
    unsigned short* As,
    const unsigned short* __restrict__ xs, int L, int Lpad, int l0, int b,
    const unsigned short* __restrict__ wt2,
    const float* __restrict__ b1, const float* __restrict__ b2,
    const float* __restrict__ b3,
    unsigned short* __restrict__ out) {
  constexpr int ROWS = NI * 16 + 2;
  constexpr int NR = NI * 16;
  const int t = threadIdx.x;
  const int w = __builtin_amdgcn_readfirstlane(t >> 6);  // cb 0..7
  const int lane = t & 63;
  const int quad = lane >> 4, lrow = lane & 15;

  // stage A: copy-only (already bf16), ROWS x 40 uint4
  for (int idx = t; idx < ROWS * 40; idx += 512) {
    int r = idx / 40, c = idx % 40;
    int l = l0 + r;
    uint4 v = make_uint4(0u, 0u, 0u, 0u);
    if (l < Lpad) v = *reinterpret_cast<const uint4*>(xs + (size_t)l * 320 + c * 8);
    *reinterpret_cast<uint4*>(&As[r * AS_STRIDE + c * 8]) = v;
  }
  __syncthreads();

  f32x4 acc[NI][3];
  #pragma unroll
  for (int ni = 0; ni < NI; ++ni)
    #pragma unroll
    for (int g = 0; g < 3; ++g) acc[ni][g] = (f32x4){0.f, 0.f, 0.f, 0.f};

  const unsigned short* wl = wt2 + (size_t)lane * 8;

  #pragma unroll 5
  for (int ec = 0; ec < 10; ++ec) {
    #pragma unroll
    for (int j = 0; j < 3; ++j) {
      bf16x8 xf[NI];
      #pragma unroll
      for (int ni = 0; ni < NI; ++ni)
        xf[ni] = *reinterpret_cast<const bf16x8*>(
            &As[(ni * 16 + lrow + j) * AS_STRIDE + ec * 32 + quad * 8]);
      #pragma unroll
      for (int g = j; g < 3; ++g) {
        const int pst = (g * (g + 1)) >> 1;
        bf16x8 wf = *reinterpret_cast<const bf16x8*>(
            wl + ((((pst + j) * 8 + w) * 10 + ec) << 9));
        #pragma unroll
        for (int ni = 0; ni < NI; ++ni)
          acc[ni][g] = __builtin_amdgcn_mfma_f32_16x16x32_bf16(
              wf, xf[ni], acc[ni][g], 0, 0, 0);
      }
    }
  }
  __syncthreads();  // all waves done reading As (psq aliases As)
  float* psq = (float*)As;  // psq[8][3][NR]

  const float* biases[3] = {b1, b2, b3};
  float4 bv[3];
  #pragma unroll
  for (int g = 0; g < 3; ++g)
    bv[g] = *reinterpret_cast<const float4*>(biases[g] + w * 16 + quad * 4);

  // per-wave ssq: register sums -> 2 shfls -> per-wave LDS slot
  #pragma unroll
  for (int ni = 0; ni < NI; ++ni) {
    #pragma unroll
    for (int g = 0; g < 3; ++g) {
      float p = 0.f;
      #pragma unroll
      for (int r = 0; r < 4; ++r) {
        float y = fmaxf(acc[ni][g][r] + bv[g][r], 0.f);
        p += y * y;
      }
      p += __shfl_xor(p, 16);
      p += __shfl_xor(p, 32);
      if (lane < 16) psq[(w * 3 + g) * NR + ni * 16 + lrow] = p;
    }
  }
  __syncthreads();

  #pragma unroll
  for (int ni = 0; ni < NI; ++ni) {
    int row = ni * 16 + lrow;
    int l = l0 + row;
    if (l < L) {
      #pragma unroll
      for (int g = 0; g < 3; ++g) {
        float ssq = 0.f;
        #pragma unroll
        for (int wv = 0; wv < 8; ++wv) ssq += psq[(wv * 3 + g) * NR + row];
        float inv = 1.0f / (sqrtf(ssq) + 1e-13f);
        unsigned int pk[2];
        #pragma unroll
        for (int h = 0; h < 2; ++h) {
          float y0 = fmaxf(acc[ni][g][2 * h + 0] + bv[g][2 * h + 0], 0.f) * inv;
          float y1 = fmaxf(acc[ni][g][2 * h + 1] + bv[g][2 * h + 1], 0.f) * inv;
          pk[h] = (unsigned int)f2bf(y0) | ((unsigned int)f2bf(y1) << 16);
        }
        unsigned short* op = out + ((size_t)(g * 128 + b) * L + l) * 128 +
                             w * 16 + quad * 4;
        *reinterpret_cast<uint2*>(op) = make_uint2(pk[0], pk[1]);
      }
    }
  }
}

// blocks 0..511: doc (b=bi>>2, l0=(bi&3)*64); 512..639: query (b=bi-512)
__global__ __launch_bounds__(512, 4) void conv_all(
    const unsigned short* __restrict__ qx, const unsigned short* __restrict__ dx,
    const unsigned short* __restrict__ wt2,
    const float* __restrict__ b1, const float* __restrict__ b2,
    const float* __restrict__ b3,
    unsigned short* __restrict__ qn, unsigned short* __restrict__ dn) {
  __shared__ unsigned short As[66 * AS_STRIDE];  // 45408 B (psq aliased)
  const int bi = blockIdx.x;
  if (bi < 512)
    conv_body<4>(As, dx + (size_t)(bi >> 2) * 256 * 320, 256, 256,
                 (bi & 3) * 64, bi >> 2, wt2, b1, b2, b3, dn);
  else
    conv_body<2>(As, qx + (size_t)(bi - 512) * 32 * 320, 30, 32,
                 0, bi - 512, wt2, b1, b2, b3, qn);
}

// One wave per (tg, b, dchunk of 32). A = doc rows (M=d), B = query rows
// (N=q), K = c = 128. fma-form RBF; quad shfl d-sum; chunk partials out.
__global__ __launch_bounds__(64) void pool_mfma(
    const unsigned short* __restrict__ qn, const unsigned short* __restrict__ dn,
    const float* __restrict__ qmask, const float* __restrict__ dmask,
    float* __restrict__ pkq8) {
  // exp(NEGC_k*(cm-MU_k)^2) = exp2(fma(w_k, cm - 2MU_k, NEGC_k*MU_k^2)),
  // w_k = NEGC_k*cm. k=0: NEGC0=-721347.52 (sigma 1e-3); k>=1: -72.134752.
  const float A2[11] = {2.0f, 1.8f, 1.4f, 1.0f, 0.6f, 0.2f,
                        -0.2f, -0.6f, -1.0f, -1.4f, -1.8f};
  const float CC[11] = {-721347.52f, -58.429149f, -35.346028f, -18.033688f,
                        -6.4921277f, -0.72134752f, -0.72134752f, -6.4921277f,
                        -18.033688f, -35.346028f, -58.429149f};
  const int tg    = blockIdx.x >> 3;
  const int chunk = blockIdx.x & 7;
  const int b     = blockIdx.y;
  const int lane  = threadIdx.x;
  const int quad  = lane >> 4, l15 = lane & 15;
  const int d0    = chunk * 32;

  const unsigned short* dslab = dn + (size_t)(tg * 128 + b) * 256 * 128;

  bf16x8 aD[2][4];
  #pragma unroll
  for (int mi = 0; mi < 2; ++mi)
    #pragma unroll
    for (int kt = 0; kt < 4; ++kt)
      aD[mi][kt] = *reinterpret_cast<const bf16x8*>(
          dslab + (size_t)(d0 + mi * 16 + l15) * 128 + kt * 32 + quad * 8);

  float dmv[2][4];
  #pragma unroll
  for (int mi = 0; mi < 2; ++mi)
    #pragma unroll
    for (int r = 0; r < 4; ++r)
      dmv[mi][r] = dmask[b * 256 + d0 + mi * 16 + quad * 4 + r];

  float qmv[2];
  qmv[0] = qmask[b * 30 + l15];
  qmv[1] = (16 + l15 < 30) ? qmask[b * 30 + 16 + l15] : 0.0f;

  #pragma unroll 1
  for (int ig = 0; ig < 3; ++ig) {
    const unsigned short* qslab = qn + (size_t)(ig * 128 + b) * 30 * 128;

    bf16x8 bQ[2][4];
    #pragma unroll
    for (int ni = 0; ni < 2; ++ni)
      #pragma unroll
      for (int kt = 0; kt < 4; ++kt)
        bQ[ni][kt] = *reinterpret_cast<const bf16x8*>(
            qslab + (size_t)(ni * 16 + l15) * 128 + kt * 32 + quad * 8);

    f32x4 acc[2][2];
    #pragma unroll
    for (int mi = 0; mi < 2; ++mi)
      #pragma unroll
      for (int ni = 0; ni < 2; ++ni) acc[mi][ni] = (f32x4){0.f, 0.f, 0.f, 0.f};

    #pragma unroll
    for (int kt = 0; kt < 4; ++kt)
      #pragma unroll
      for (int mi = 0; mi < 2; ++mi)
        #pragma unroll
        for (int ni = 0; ni < 2; ++ni)
          acc[mi][ni] = __builtin_amdgcn_mfma_f32_16x16x32_bf16(
              aD[mi][kt], bQ[ni][kt], acc[mi][ni], 0, 0, 0);

    float feat[2][11];
    #pragma unroll
    for (int ni = 0; ni < 2; ++ni)
      #pragma unroll
      for (int kk = 0; kk < 11; ++kk) feat[ni][kk] = 0.0f;

    #pragma unroll
    for (int mi = 0; mi < 2; ++mi) {
      #pragma unroll
      for (int r = 0; r < 4; ++r) {
        #pragma unroll
        for (int ni = 0; ni < 2; ++ni) {
          float m  = qmv[ni] * dmv[mi][r];
          float cm = acc[mi][ni][r] * m;
          float w0 = cm * -721347.52f;
          float w1 = cm * -72.134752f;
          #pragma unroll
          for (int kk = 0; kk < 11; ++kk) {
            float wk = (kk == 0) ? w0 : w1;
            float e = EXP2F(fmaf(wk, cm - A2[kk], CC[kk]));
            feat[ni][kk] += e * m;
          }
        }
      }
    }

    #pragma unroll
    for (int ni = 0; ni < 2; ++ni)
      #pragma unroll
      for (int kk = 0; kk < 11; ++kk) {
        float v = feat[ni][kk];
        v += __shfl_xor(v, 16);
        v += __shfl_xor(v, 32);
        feat[ni][kk] = v;
      }

    if (quad == 0) {
      const int pair = ig * 3 + tg;
      #pragma unroll
      for (int ni = 0; ni < 2; ++ni) {
        int q = ni * 16 + l15;
        if (q < 30) {
          float* p = pkq8 +
              (((size_t)(chunk * 9 + pair) * 128 + b) * 30 + q) * 11;
          #pragma unroll
          for (int kk = 0; kk < 11; ++kk) p[kk] = feat[ni][kk];
        }
      }
    }
  }
}

__global__ __launch_bounds__(256) void final_kernel(
    const float* __restrict__ pkq8, const float* __restrict__ qmask,
    const float* __restrict__ dw, float* __restrict__ out) {
  const int CH = 9 * 128 * 30 * 11;  // 380160
  const int b = blockIdx.x;
  const int t = threadIdx.x;
  float s = 0.0f;
  for (int idx = t; idx < 9 * 30 * 11; idx += 256) {
    int pair = idx / 330;
    int rem  = idx % 330;
    int q    = rem / 11;
    int kk   = rem % 11;
    size_t base = (((size_t)pair * 128 + b) * 30 + q) * 11 + kk;
    float v = 0.f;
    #pragma unroll
    for (int c = 0; c < 8; ++c) v += pkq8[base + (size_t)c * CH];
    s += __logf(fmaxf(v, 1e-10f)) * 0.01f * qmask[b * 30 + q] * dw[pair * 11 + kk];
  }
  s += __shfl_xor(s, 1);  s += __shfl_xor(s, 2);  s += __shfl_xor(s, 4);
  s += __shfl_xor(s, 8);  s += __shfl_xor(s, 16); s += __shfl_xor(s, 32);
  __shared__ float part[4];
  if ((t & 63) == 0) part[t >> 6] = s;
  __syncthreads();
  if (t == 0) out[b] = part[0] + part[1] + part[2] + part[3];
}

extern "C" void kernel_launch(void* const* d_in, const int* in_sizes, int n_in,
                              void* d_out, int out_size, void* d_ws, size_t ws_size,
                              hipStream_t stream) {
  const float* qemb  = (const float*)d_in[0];
  const float* demb  = (const float*)d_in[1];
  const float* qmask = (const float*)d_in[2];
  const float* dmask = (const float*)d_in[3];
  const float* w1 = (const float*)d_in[4];
  const float* b1 = (const float*)d_in[5];
  const float* w2 = (const float*)d_in[6];
  const float* b2 = (const float*)d_in[7];
  const float* w3 = (const float*)d_in[8];
  const float* b3 = (const float*)d_in[9];
  const float* dw = (const float*)d_in[10];

  unsigned short* ws  = (unsigned short*)d_ws;
  unsigned short* wt2 = ws;                    // 245760
  unsigned short* qx  = ws + 245760;           // 1310720
  unsigned short* dx  = ws + 1556480;          // 10485760
  unsigned short* qn  = ws + 12042240;         // 1474560
  unsigned short* dn  = ws + 13516800;         // 12582912
  float*          pkq8 = (float*)(ws + 245760); // aliased over qx/dx
  float* out = (float*)d_out;

  prep<<<6720, 256, 0, stream>>>(w1, w2, w3, qemb, demb, wt2, qx, dx);
  conv_all<<<640, 512, 0, stream>>>(qx, dx, wt2, b1, b2, b3, qn, dn);
  pool_mfma<<<dim3(24, 128), 64, 0, stream>>>(qn, dn, qmask, dmask, pkq8);
  final_kernel<<<128, 256, 0, stream>>>(pkq8, qmask, dw, out);
}

// Round 12
// 177.581 us; speedup vs baseline: 1.3001x; 1.0098x over previous
//
#include <hip/hip_runtime.h>
#include <math.h>

// Conv-KNRM on MI355X. B=128, QLEN=30, DLEN=256, EMB=300 (pad 320), C=128.
//
// 4 dispatches:
//   prep      : wt2 bf16 frag-order [plane(6)][cb(8)][ec(10)][lane(64)][8];
//               qemb/demb fp32 -> bf16 rows [*][320].
//   conv_all  : 640 blocks x 512 thr (8 waves; wave = one cb: 16ch x 3 grams).
//               Doc 64-row tiles / query 32-row. A=w frags global (L2),
//               B=x rows LDS, unroll 2 (R8 body: measured 46.4-47.5 us x5).
//               bias+relu+L2norm, packed uint2 -> bf16 [g][b][l][c].
//   pool_mfma : 3072 single-wave blocks (tg,b,dchunk32). MFMA cos, fma-form
//               RBF x11, quad shfl d-sum -> pkq8 partials.
//   final     : sum 8 chunks, log/clip/qmask/sum_q dot dense_w -> out[128].
//
// ws (shorts): wt2@0 (245760) | qx@245760 (1310720) | dx@1556480 (10485760)
//              | qn@12042240 (1474560) | dn@13516800 (12582912)
// pkq8 (f32 12.2MB) aliased over qx/dx (dead after conv_all).

typedef __bf16 bf16x8 __attribute__((ext_vector_type(8)));
typedef float f32x4 __attribute__((ext_vector_type(4)));

#if __has_builtin(__builtin_amdgcn_exp2f)
#define EXP2F(x) __builtin_amdgcn_exp2f(x)
#else
#define EXP2F(x) exp2f(x)
#endif

#define AS_STRIDE 344  // shorts; 688 B row: 2-way b128 (free), 16B-aligned

static __device__ __forceinline__ unsigned short f2bf(float f) {
  union { float f; unsigned int u; } v; v.f = f;
  unsigned int r = v.u + 0x7FFFu + ((v.u >> 16) & 1u);  // RNE
  return (unsigned short)(r >> 16);
}

// blocks [0,960): weights -> frag order; [960,6720): x -> bf16
__global__ __launch_bounds__(256) void prep(
    const float* __restrict__ w1, const float* __restrict__ w2,
    const float* __restrict__ w3,
    const float* __restrict__ qemb, const float* __restrict__ demb,
    unsigned short* __restrict__ wt2,
    unsigned short* __restrict__ qx, unsigned short* __restrict__ dx) {
  const int bid = blockIdx.x;
  const int t = threadIdx.x;
  if (bid < 960) {
    int idx = bid * 256 + t;
    if (idx >= 245760) return;
    int jj   = idx & 7;
    int lane = (idx >> 3) & 63;
    int ec   = (idx >> 9) % 10;
    int cb   = (idx / 5120) & 7;
    int p    = idx / 40960;
    const float* w; int k, jt;
    if (p == 0)      { w = w1; k = 1; jt = 0; }
    else if (p <= 2) { w = w2; k = 2; jt = p - 1; }
    else             { w = w3; k = 3; jt = p - 3; }
    int c = cb * 16 + (lane & 15);
    int e = ec * 32 + (lane >> 4) * 8 + jj;
    float v = (e < 300) ? w[(c * 300 + e) * k + jt] : 0.0f;
    wt2[idx] = f2bf(v);
  } else {
    int idx = (bid - 960) * 256 + t;
    if (idx >= 1474560) return;
    int c8   = idx % 40;
    int ridx = idx / 40;
    const float* src; unsigned short* dst; int valid;
    if (ridx < 4096) {
      int b = ridx >> 5, r = ridx & 31;
      valid = (r < 30);
      src = qemb + ((size_t)b * 30 + r) * 300;
      dst = qx + (size_t)ridx * 320;
    } else {
      int rd = ridx - 4096;
      valid = 1;
      src = demb + (size_t)rd * 300;
      dst = dx + (size_t)rd * 320;
    }
    int e = c8 * 8;
    float4 a = make_float4(0.f, 0.f, 0.f, 0.f);
    float4 c = make_float4(0.f, 0.f, 0.f, 0.f);
    if (valid && e < 300)     a = *reinterpret_cast<const float4*>(src + e);
    if (valid && e + 4 < 300) c = *reinterpret_cast<const float4*>(src + e + 4);
    uint4 o;
    o.x = (unsigned int)f2bf(a.x) | ((unsigned int)f2bf(a.y) << 16);
    o.y = (unsigned int)f2bf(a.z) | ((unsigned int)f2bf(a.w) << 16);
    o.z = (unsigned int)f2bf(c.x) | ((unsigned int)f2bf(c.y) << 16);
    o.w = (unsigned int)f2bf(c.z) | ((unsigned int)f2bf(c.w) << 16);
    *reinterpret_cast<uint4*>(dst + e) = o;
  }
}

// Wave tile: NI*16 l-rows x 48 ch (cb=w: 16 ch in each of 3 grams).
// A-operand = weights (frag-order global), B = x rows (LDS).
// D: ch = cb*16 + quad*4 + r, l = ni*16 + lrow.  (R8 body, unroll 2)
template<int NI>
__device__ __forceinline__ void conv_body(
    unsigned short* As, float* psq,  // psq[8][3][NI*16]
    const unsigned short* __restrict__ xs, int L, int Lpad, int l0, int b,
    const unsigned short* __restrict__ wt2,
    const float* __restrict__ b1, const float* __restrict__ b2,
    const float* __restrict__ b3,
    unsigned short* __restrict__ out) {
  constexpr int ROWS = NI * 16 + 2;
  constexpr int NR = NI * 16;
  const int t = threadIdx.x;
  const int w = __builtin_amdgcn_readfirstlane(t >> 6);  // cb 0..7
  const int lane = t & 63;
  const int quad = lane >> 4, lrow = lane & 15;

  // stage A: copy-only (already bf16), ROWS x 40 uint4
  for (int idx = t; idx < ROWS * 40; idx += 512) {
    int r = idx / 40, c = idx % 40;
    int l = l0 + r;
    uint4 v = make_uint4(0u, 0u, 0u, 0u);
    if (l < Lpad) v = *reinterpret_cast<const uint4*>(xs + (size_t)l * 320 + c * 8);
    *reinterpret_cast<uint4*>(&As[r * AS_STRIDE + c * 8]) = v;
  }
  __syncthreads();

  f32x4 acc[NI][3];
  #pragma unroll
  for (int ni = 0; ni < NI; ++ni)
    #pragma unroll
    for (int g = 0; g < 3; ++g) acc[ni][g] = (f32x4){0.f, 0.f, 0.f, 0.f};

  const unsigned short* wl = wt2 + (size_t)lane * 8;

  #pragma unroll 2
  for (int ec = 0; ec < 10; ++ec) {
    #pragma unroll
    for (int j = 0; j < 3; ++j) {
      bf16x8 xf[NI];
      #pragma unroll
      for (int ni = 0; ni < NI; ++ni)
        xf[ni] = *reinterpret_cast<const bf16x8*>(
            &As[(ni * 16 + lrow + j) * AS_STRIDE + ec * 32 + quad * 8]);
      #pragma unroll
      for (int g = j; g < 3; ++g) {
        const int pst = (g * (g + 1)) >> 1;
        bf16x8 wf = *reinterpret_cast<const bf16x8*>(
            wl + ((((pst + j) * 8 + w) * 10 + ec) << 9));
        #pragma unroll
        for (int ni = 0; ni < NI; ++ni)
          acc[ni][g] = __builtin_amdgcn_mfma_f32_16x16x32_bf16(
              wf, xf[ni], acc[ni][g], 0, 0, 0);
      }
    }
  }

  const float* biases[3] = {b1, b2, b3};
  float4 bv[3];
  #pragma unroll
  for (int g = 0; g < 3; ++g)
    bv[g] = *reinterpret_cast<const float4*>(biases[g] + w * 16 + quad * 4);

  // per-wave ssq: register sums -> 2 shfls -> per-wave LDS slot
  #pragma unroll
  for (int ni = 0; ni < NI; ++ni) {
    #pragma unroll
    for (int g = 0; g < 3; ++g) {
      float p = 0.f;
      #pragma unroll
      for (int r = 0; r < 4; ++r) {
        float y = fmaxf(acc[ni][g][r] + bv[g][r], 0.f);
        p += y * y;
      }
      p += __shfl_xor(p, 16);
      p += __shfl_xor(p, 32);
      if (lane < 16) psq[(w * 3 + g) * NR + ni * 16 + lrow] = p;
    }
  }
  __syncthreads();

  #pragma unroll
  for (int ni = 0; ni < NI; ++ni) {
    int row = ni * 16 + lrow;
    int l = l0 + row;
    if (l < L) {
      #pragma unroll
      for (int g = 0; g < 3; ++g) {
        float ssq = 0.f;
        #pragma unroll
        for (int wv = 0; wv < 8; ++wv) ssq += psq[(wv * 3 + g) * NR + row];
        float inv = 1.0f / (sqrtf(ssq) + 1e-13f);
        unsigned int pk[2];
        #pragma unroll
        for (int h = 0; h < 2; ++h) {
          float y0 = fmaxf(acc[ni][g][2 * h + 0] + bv[g][2 * h + 0], 0.f) * inv;
          float y1 = fmaxf(acc[ni][g][2 * h + 1] + bv[g][2 * h + 1], 0.f) * inv;
          pk[h] = (unsigned int)f2bf(y0) | ((unsigned int)f2bf(y1) << 16);
        }
        unsigned short* op = out + ((size_t)(g * 128 + b) * L + l) * 128 +
                             w * 16 + quad * 4;
        *reinterpret_cast<uint2*>(op) = make_uint2(pk[0], pk[1]);
      }
    }
  }
}

// blocks 0..511: doc (b=bi>>2, l0=(bi&3)*64); 512..639: query (b=bi-512)
__global__ __launch_bounds__(512, 4) void conv_all(
    const unsigned short* __restrict__ qx, const unsigned short* __restrict__ dx,
    const unsigned short* __restrict__ wt2,
    const float* __restrict__ b1, const float* __restrict__ b2,
    const float* __restrict__ b3,
    unsigned short* __restrict__ qn, unsigned short* __restrict__ dn) {
  __shared__ unsigned short As[66 * AS_STRIDE];
  __shared__ float psq[8 * 3 * 64];
  const int bi = blockIdx.x;
  if (bi < 512)
    conv_body<4>(As, psq, dx + (size_t)(bi >> 2) * 256 * 320, 256, 256,
                 (bi & 3) * 64, bi >> 2, wt2, b1, b2, b3, dn);
  else
    conv_body<2>(As, psq, qx + (size_t)(bi - 512) * 32 * 320, 30, 32,
                 0, bi - 512, wt2, b1, b2, b3, qn);
}

// One wave per (tg, b, dchunk of 32). A = doc rows (M=d), B = query rows
// (N=q), K = c = 128. fma-form RBF; quad shfl d-sum; chunk partials out.
__global__ __launch_bounds__(64) void pool_mfma(
    const unsigned short* __restrict__ qn, const unsigned short* __restrict__ dn,
    const float* __restrict__ qmask, const float* __restrict__ dmask,
    float* __restrict__ pkq8) {
  // exp(NEGC_k*(cm-MU_k)^2) = exp2(fma(w_k, cm - 2MU_k, NEGC_k*MU_k^2)),
  // w_k = NEGC_k*cm. k=0: NEGC0=-721347.52 (sigma 1e-3); k>=1: -72.134752.
  const float A2[11] = {2.0f, 1.8f, 1.4f, 1.0f, 0.6f, 0.2f,
                        -0.2f, -0.6f, -1.0f, -1.4f, -1.8f};
  const float CC[11] = {-721347.52f, -58.429149f, -35.346028f, -18.033688f,
                        -6.4921277f, -0.72134752f, -0.72134752f, -6.4921277f,
                        -18.033688f, -35.346028f, -58.429149f};
  const int tg    = blockIdx.x >> 3;
  const int chunk = blockIdx.x & 7;
  const int b     = blockIdx.y;
  const int lane  = threadIdx.x;
  const int quad  = lane >> 4, l15 = lane & 15;
  const int d0    = chunk * 32;

  const unsigned short* dslab = dn + (size_t)(tg * 128 + b) * 256 * 128;

  bf16x8 aD[2][4];
  #pragma unroll
  for (int mi = 0; mi < 2; ++mi)
    #pragma unroll
    for (int kt = 0; kt < 4; ++kt)
      aD[mi][kt] = *reinterpret_cast<const bf16x8*>(
          dslab + (size_t)(d0 + mi * 16 + l15) * 128 + kt * 32 + quad * 8);

  float dmv[2][4];
  #pragma unroll
  for (int mi = 0; mi < 2; ++mi)
    #pragma unroll
    for (int r = 0; r < 4; ++r)
      dmv[mi][r] = dmask[b * 256 + d0 + mi * 16 + quad * 4 + r];

  float qmv[2];
  qmv[0] = qmask[b * 30 + l15];
  qmv[1] = (16 + l15 < 30) ? qmask[b * 30 + 16 + l15] : 0.0f;

  #pragma unroll 1
  for (int ig = 0; ig < 3; ++ig) {
    const unsigned short* qslab = qn + (size_t)(ig * 128 + b) * 30 * 128;

    bf16x8 bQ[2][4];
    #pragma unroll
    for (int ni = 0; ni < 2; ++ni)
      #pragma unroll
      for (int kt = 0; kt < 4; ++kt)
        bQ[ni][kt] = *reinterpret_cast<const bf16x8*>(
            qslab + (size_t)(ni * 16 + l15) * 128 + kt * 32 + quad * 8);

    f32x4 acc[2][2];
    #pragma unroll
    for (int mi = 0; mi < 2; ++mi)
      #pragma unroll
      for (int ni = 0; ni < 2; ++ni) acc[mi][ni] = (f32x4){0.f, 0.f, 0.f, 0.f};

    #pragma unroll
    for (int kt = 0; kt < 4; ++kt)
      #pragma unroll
      for (int mi = 0; mi < 2; ++mi)
        #pragma unroll
        for (int ni = 0; ni < 2; ++ni)
          acc[mi][ni] = __builtin_amdgcn_mfma_f32_16x16x32_bf16(
              aD[mi][kt], bQ[ni][kt], acc[mi][ni], 0, 0, 0);

    float feat[2][11];
    #pragma unroll
    for (int ni = 0; ni < 2; ++ni)
      #pragma unroll
      for (int kk = 0; kk < 11; ++kk) feat[ni][kk] = 0.0f;

    #pragma unroll
    for (int mi = 0; mi < 2; ++mi) {
      #pragma unroll
      for (int r = 0; r < 4; ++r) {
        #pragma unroll
        for (int ni = 0; ni < 2; ++ni) {
          float m  = qmv[ni] * dmv[mi][r];
          float cm = acc[mi][ni][r] * m;
          float w0 = cm * -721347.52f;
          float w1 = cm * -72.134752f;
          #pragma unroll
          for (int kk = 0; kk < 11; ++kk) {
            float wk = (kk == 0) ? w0 : w1;
            float e = EXP2F(fmaf(wk, cm - A2[kk], CC[kk]));
            feat[ni][kk] += e * m;
          }
        }
      }
    }

    #pragma unroll
    for (int ni = 0; ni < 2; ++ni)
      #pragma unroll
      for (int kk = 0; kk < 11; ++kk) {
        float v = feat[ni][kk];
        v += __shfl_xor(v, 16);
        v += __shfl_xor(v, 32);
        feat[ni][kk] = v;
      }

    if (quad == 0) {
      const int pair = ig * 3 + tg;
      #pragma unroll
      for (int ni = 0; ni < 2; ++ni) {
        int q = ni * 16 + l15;
        if (q < 30) {
          float* p = pkq8 +
              (((size_t)(chunk * 9 + pair) * 128 + b) * 30 + q) * 11;
          #pragma unroll
          for (int kk = 0; kk < 11; ++kk) p[kk] = feat[ni][kk];
        }
      }
    }
  }
}

__global__ __launch_bounds__(256) void final_kernel(
    const float* __restrict__ pkq8, const float* __restrict__ qmask,
    const float* __restrict__ dw, float* __restrict__ out) {
  const int CH = 9 * 128 * 30 * 11;  // 380160
  const int b = blockIdx.x;
  const int t = threadIdx.x;
  float s = 0.0f;
  for (int idx = t; idx < 9 * 30 * 11; idx += 256) {
    int pair = idx / 330;
    int rem  = idx % 330;
    int q    = rem / 11;
    int kk   = rem % 11;
    size_t base = (((size_t)pair * 128 + b) * 30 + q) * 11 + kk;
    float v = 0.f;
    #pragma unroll
    for (int c = 0; c < 8; ++c) v += pkq8[base + (size_t)c * CH];
    s += __logf(fmaxf(v, 1e-10f)) * 0.01f * qmask[b * 30 + q] * dw[pair * 11 + kk];
  }
  s += __shfl_xor(s, 1);  s += __shfl_xor(s, 2);  s += __shfl_xor(s, 4);
  s += __shfl_xor(s, 8);  s += __shfl_xor(s, 16); s += __shfl_xor(s, 32);
  __shared__ float part[4];
  if ((t & 63) == 0) part[t >> 6] = s;
  __syncthreads();
  if (t == 0) out[b] = part[0] + part[1] + part[2] + part[3];
}

extern "C" void kernel_launch(void* const* d_in, const int* in_sizes, int n_in,
                              void* d_out, int out_size, void* d_ws, size_t ws_size,
                              hipStream_t stream) {
  const float* qemb  = (const float*)d_in[0];
  const float* demb  = (const float*)d_in[1];
  const float* qmask = (const float*)d_in[2];
  const float* dmask = (const float*)d_in[3];
  const float* w1 = (const float*)d_in[4];
  const float* b1 = (const float*)d_in[5];
  const float* w2 = (const float*)d_in[6];
  const float* b2 = (const float*)d_in[7];
  const float* w3 = (const float*)d_in[8];
  const float* b3 = (const float*)d_in[9];
  const float* dw = (const float*)d_in[10];

  unsigned short* ws  = (unsigned short*)d_ws;
  unsigned short* wt2 = ws;                    // 245760
  unsigned short* qx  = ws + 245760;           // 1310720
  unsigned short* dx  = ws + 1556480;          // 10485760
  unsigned short* qn  = ws + 12042240;         // 1474560
  unsigned short* dn  = ws + 13516800;         // 12582912
  float*          pkq8 = (float*)(ws + 245760); // aliased over qx/dx
  float* out = (float*)d_out;

  prep<<<6720, 256, 0, stream>>>(w1, w2, w3, qemb, demb, wt2, qx, dx);
  conv_all<<<640, 512, 0, stream>>>(qx, dx, wt2, b1, b2, b3, qn, dn);
  pool_mfma<<<dim3(24, 128), 64, 0, stream>>>(qn, dn, qmask, dmask, pkq8);
  final_kernel<<<128, 256, 0, stream>>>(pkq8, qmask, dw, out);
}